// Round 16
// baseline (1695.324 us; speedup 1.0000x reference)
//
#include <hip/hip_runtime.h>
#include <stdint.h>

// FixedConv1DPriorEnsemble: DZ=30 ensemble of conv nets over embedded tokens.
// V=32000 E=8 DZ=30 C=10, CH=(4,8,8), K=3, S=(2,2,1), B=512, L=4096.
//
// History: R11 318.7 (f16 dot2); R13 256.3 (MFMA stages 2/3); R15 243.4 BEST
//   (merged full-sequence blocks, ens 169.5). Residual analysis: ~74us of
//   non-ensemble time tracks GRAPH NODE COUNT (~20us/node), not work; LDS
//   conflicts 10.4M cyc from h1 quad-stride 1028 dwords = 4 mod 32 (4-way).
// R16: (1) reduce folded into ensemble via last-block pattern (fence +
//   device atomic counter, agent-scope atomic loads to dodge per-XCD L2
//   staleness); counter zeroed by prep. 3 nodes -> 2.
//   (2) h1 stride 2056 -> 2066 f16 (1033 dwords, odd mod 32: 4-way -> 2-way).

typedef _Float16 f16;
typedef f16 f16x2 __attribute__((ext_vector_type(2)));
typedef f16 f16x4 __attribute__((ext_vector_type(4)));
typedef f16 f16x8 __attribute__((ext_vector_type(8)));
typedef float f32x4 __attribute__((ext_vector_type(4)));

#define H1S 2066   // h1 row stride (f16): 1033 dwords, odd mod 32

static __device__ __forceinline__ float dot2(f16x2 a, f16x2 b, float c) {
#if __has_builtin(__builtin_amdgcn_fdot2)
  return __builtin_amdgcn_fdot2(a, b, c, false);
#else
  return fmaf((float)a.x, (float)b.x, fmaf((float)a.y, (float)b.y, c));
#endif
}
static __device__ __forceinline__ f16x2 ldh(uint32_t u) {
  union { uint32_t u; f16x2 h; } v; v.u = u; return v.h;
}
static __device__ __forceinline__ uint32_t bch(f16x2 h) {
  union { uint32_t u; f16x2 h; } v; v.h = h; return v.u;
}
static __device__ __forceinline__ uint32_t packh(float a, float b) {
  f16x2 p; p.x = (f16)a; p.y = (f16)b; return bch(p);
}

// ---- prep: embed x_f16 + stage-1 dot2 weights + stage-2/3 MFMA A-frags ----
__global__ __launch_bounds__(256) void prep_kernel(
    const int* __restrict__ ids, const float* __restrict__ mask,
    const float* __restrict__ tbl,
    const float* __restrict__ W1, const float* __restrict__ W2,
    const float* __restrict__ W3,
    f16* __restrict__ x, uint32_t* __restrict__ wp,
    f16* __restrict__ a2, f16* __restrict__ a3,
    unsigned int* __restrict__ counter) {
  const int blk = blockIdx.x;
  if (blk < 4096) {                            // embed: 2 tokens/thread
    const int b  = blk >> 3;
    const int l0 = ((blk & 7) * 256 + threadIdx.x) * 2;
    const int2   iv = *(const int2*)(ids + (size_t)b * 4096 + l0);
    const float2 mv = *(const float2*)(mask + (size_t)b * 4096 + l0);
    const float4* t4 = (const float4*)tbl;
    const float4 a0 = t4[(size_t)iv.x * 2], A1 = t4[(size_t)iv.x * 2 + 1];
    const float4 c0 = t4[(size_t)iv.y * 2], C1 = t4[(size_t)iv.y * 2 + 1];
    const float r0[8] = {a0.x, a0.y, a0.z, a0.w, A1.x, A1.y, A1.z, A1.w};
    const float r1[8] = {c0.x, c0.y, c0.z, c0.w, C1.x, C1.y, C1.z, C1.w};
    f16* xb = x + (size_t)b * 8 * 4096 + l0;
    #pragma unroll
    for (int e = 0; e < 8; ++e) {
      f16x2 p; p.x = (f16)(r0[e] * mv.x); p.y = (f16)(r1[e] * mv.y);
      *(f16x2*)(xb + e * 4096) = p;
    }
  } else {
    if (blk == gridDim.x - 1 && threadIdx.x == 255) *counter = 0u;
    const int i = (blk - 4096) * 256 + threadIdx.x;
    if (i < 960) {                             // wp: 30*32
      const int d = i / 32, r = i % 32, e = r / 4, c = r % 4;
      const float* w = W1 + d * 96 + c * 24 + e * 3;
      wp[d * 64 + r * 2 + 0] = packh(w[0], w[1]);
      wp[d * 64 + r * 2 + 1] = packh(w[2], 0.0f);
    } else if (i < 2880) {                     // a2: 30*64
      const int idx = i - 960, d = idx >> 6, lane = idx & 63;
      const int quad = lane >> 4, m = lane & 15;
      f16x8 v;
      #pragma unroll
      for (int j = 0; j < 8; ++j) {
        float val = 0.0f;
        if (m < 8)  { if (j < 3)           val = W2[d * 96 + m * 12 + quad * 3 + j]; }
        else        { if (j >= 2 && j < 5) val = W2[d * 96 + (m - 8) * 12 + quad * 3 + (j - 2)]; }
        v[j] = (f16)val;
      }
      *(f16x8*)(a2 + ((size_t)d * 64 + lane) * 8) = v;
    } else if (i < 4800) {                     // a3: 30*64
      const int idx = i - 2880, d = idx >> 6, lane = idx & 63;
      const int quad = lane >> 4, m = lane & 15;
      f16x8 v;
      #pragma unroll
      for (int j = 0; j < 8; ++j) {
        const int c2 = quad * 2 + (j >> 2), t = j & 3;
        float val = 0.0f;
        if (m < 8)  { if (t < 3)  val = W3[d * 192 + m * 24 + c2 * 3 + t]; }
        else        { if (t >= 1) val = W3[d * 192 + (m - 8) * 24 + c2 * 3 + (t - 1)]; }
        v[j] = (f16)val;
      }
      *(f16x8*)(a3 + ((size_t)d * 64 + lane) * 8) = v;
    }
  }
}

// ---------------- fast path: one block per (b,d) + last-block reduce ----------------
__global__ __launch_bounds__(256, 8) void ensemble_f16_kernel(
    const f16* __restrict__ x,        // [512][8][4096]
    const uint32_t* __restrict__ wp,  // stage-1 packed weights
    const f16* __restrict__ a2,       // stage-2 A-fragments [30][64][8]
    const f16* __restrict__ a3,       // stage-3 A-fragments [30][64][8]
    const float* __restrict__ z,
    const float* __restrict__ b1, const float* __restrict__ b2,
    const float* __restrict__ b3,
    const float* __restrict__ Wh, const float* __restrict__ bh,
    float* __restrict__ part,         // [30][512][10]
    unsigned int* __restrict__ counter,
    float* __restrict__ out)          // [512][10]
{
  const int tid = threadIdx.x;
  const int b   = blockIdx.x / 30;    // same-b blocks consecutive (x L2 reuse)
  const int d   = blockIdx.x - b * 30;

  // h1 f16[4][2066] (16528B); h2 f16[8][1028] overlay; pool f32[8][128] overlay
  __shared__ float smem[4136];
  __shared__ float pooled[8];
  __shared__ int   sflag;
  f16* h1f = (f16*)smem;
  f16* h2f = (f16*)smem;

  const f16*      xb  = x + (size_t)b * 8 * 4096;
  const uint32_t* wq1 = wp + d * 64;

  const int w = tid >> 6, lane = tid & 63, quad = lane >> 4, n = lane & 15;

  // zero h1 pads [2047,2066) x 4 rows (stage-2 tiles over-read up to 2051)
  if (tid < 76) h1f[(tid / 19) * H1S + 2047 + (tid % 19)] = (f16)0.0f;
  __syncthreads();

  // ---- stage 1: conv1 (E=8 -> 4ch, K=3, stride 2), dot2, 8 outputs/thread ----
  {
    float bia[4];
    #pragma unroll
    for (int c = 0; c < 4; ++c) bia[c] = b1[d * 4 + c];

    #pragma unroll
    for (int g = 0; g < 2; ++g) {
      const int l0 = 8 * tid + 4 * g;         // outputs l0..l0+3 (covers 0..2047)
      const int p0 = 2 * l0;                  // 16B-aligned byte offset
      const bool edge = (p0 + 8 >= 4096);     // only tid==255, g==1

      float A[4][4];
      #pragma unroll
      for (int c = 0; c < 4; ++c)
        #pragma unroll
        for (int o = 0; o < 4; ++o) A[c][o] = bia[c];

      #pragma unroll
      for (int e = 0; e < 8; ++e) {           // fully unrolled (R3 lesson)
        const f16* xe = xb + e * 4096 + p0;
        const f16x4 va = *(const f16x4*)xe;         // P0 P1
        const f16x4 vb = *(const f16x4*)(xe + 4);   // P2 P3
        f16x2 P4;
        if (edge) { P4.x = (f16)0.0f; P4.y = (f16)0.0f; }
        else      { P4 = *(const f16x2*)(xe + 8); }
        const f16x2 P0 = va.lo, P1 = va.hi, P2 = vb.lo, P3 = vb.hi;
        #pragma unroll
        for (int c = 0; c < 4; ++c) {
          const f16x2 w01 = ldh(wq1[(e * 4 + c) * 2]);
          const f16x2 w20 = ldh(wq1[(e * 4 + c) * 2 + 1]);
          A[c][0] = dot2(P0, w01, A[c][0]); A[c][0] = dot2(P1, w20, A[c][0]);
          A[c][1] = dot2(P1, w01, A[c][1]); A[c][1] = dot2(P2, w20, A[c][1]);
          A[c][2] = dot2(P2, w01, A[c][2]); A[c][2] = dot2(P3, w20, A[c][2]);
          A[c][3] = dot2(P3, w01, A[c][3]); A[c][3] = dot2(P4, w20, A[c][3]);
        }
      }
      if (l0 + 3 < 2047) {                    // all but tid255 g1
        #pragma unroll
        for (int c = 0; c < 4; ++c) {
          f16x4 p;
          p.x = (f16)fmaxf(A[c][0], 0.0f); p.y = (f16)fmaxf(A[c][1], 0.0f);
          p.z = (f16)fmaxf(A[c][2], 0.0f); p.w = (f16)fmaxf(A[c][3], 0.0f);
          *(f16x4*)(h1f + c * H1S + l0) = p;  // 8B-aligned ds_write_b64
        }
      } else {                                // tid255 g1: outputs 2044..2046
        #pragma unroll
        for (int c = 0; c < 4; ++c)
          #pragma unroll
          for (int o = 0; o < 4; ++o)
            if (l0 + o < 2047)
              h1f[c * H1S + l0 + o] = (f16)fmaxf(A[c][o], 0.0f);
      }
    }
  }
  __syncthreads();

  // ---- stage 2 (MFMA): rows 0-7 = c2 @ j, rows 8-15 = c2 @ j+1; 32 tiles ----
  f32x4 Ci[8];
  {
    const f16x8 af2 = *(const f16x8*)(a2 + ((size_t)d * 64 + lane) * 8);
    const f32x4 cinit2 = *(const f32x4*)(b2 + d * 8 + (quad & 1) * 4);
    #pragma unroll
    for (int i = 0; i < 8; ++i) {
      const int t = w + 4 * i;                // 0..31, all valid
      const f16* bp = h1f + quad * H1S + 64 * t + 4 * n;
      union { f16x8 v; f16x2 q[4]; } u;
      u.q[0] = *(const f16x2*)bp;
      u.q[1] = *(const f16x2*)(bp + 2);
      u.q[2] = *(const f16x2*)(bp + 4);
      u.q[3] = *(const f16x2*)(bp + 6);
      Ci[i] = __builtin_amdgcn_mfma_f32_16x16x32_f16(af2, u.v, cinit2, 0, 0, 0);
    }
  }
  __syncthreads();               // all h1 reads done; overlay h2

  {
    const int shift = quad >> 1;
    const int c2b   = (quad & 1) * 4;
    #pragma unroll
    for (int i = 0; i < 8; ++i) {
      const int t  = w + 4 * i;
      const int jl = 32 * t + 2 * n + shift;
      if (jl < 1023) {
        #pragma unroll
        for (int r = 0; r < 4; ++r)
          h2f[(c2b + r) * 1028 + jl] = (f16)fmaxf(Ci[i][r], 0.0f);
      }
    }
    if (tid < 40)                // zero h2 pads [1023,1028) x 8 rows
      h2f[(tid / 5) * 1028 + 1023 + (tid % 5)] = (f16)0.0f;
  }
  __syncthreads();

  // ---- stage 3 (MFMA): rows 0-7 = cc @ p, rows 8-15 = cc @ p+1; pool ----
  float pool4[4] = {0.0f, 0.0f, 0.0f, 0.0f};
  {
    const f16x8 af3 = *(const f16x8*)(a3 + ((size_t)d * 64 + lane) * 8);
    const f32x4 cinit3 = *(const f32x4*)(b3 + d * 8 + (quad & 1) * 4);
    const int c2a = quad * 2;
    #pragma unroll
    for (int i = 0; i < 8; ++i) {
      const int t = w + 4 * i;                // 0..31, all valid
      const f16* bp = h2f + c2a * 1028 + 32 * t + 2 * n;
      union { f16x8 v; f16x2 q[4]; } u;
      u.q[0] = *(const f16x2*)bp;
      u.q[1] = *(const f16x2*)(bp + 2);
      u.q[2] = *(const f16x2*)(bp + 1028);
      u.q[3] = *(const f16x2*)(bp + 1030);
      const f32x4 C = __builtin_amdgcn_mfma_f32_16x16x32_f16(af3, u.v, cinit3, 0, 0, 0);
      const int pl = 32 * t + 2 * n + (quad >> 1);
      if (pl < 1021) {
        #pragma unroll
        for (int r = 0; r < 4; ++r) pool4[r] += fmaxf(C[r], 0.0f);
      }
    }
  }

  // ---- pool reduction: smem f32[8][128], exact cover, then shuffle ----
  __syncthreads();               // stage-3 h2 reads complete before overwrite
  {
    const int cidx = w * 32 + (quad >> 1) * 16 + n;   // 0..127, unique
    const int ccb  = (quad & 1) * 4;
    #pragma unroll
    for (int r = 0; r < 4; ++r) smem[(ccb + r) * 128 + cidx] = pool4[r];
  }
  __syncthreads();
  {
    const int rc = tid >> 5;     // channel 0..7
    const int rj = tid & 31;
    float s = smem[rc * 128 + rj]      + smem[rc * 128 + rj + 32]
            + smem[rc * 128 + rj + 64] + smem[rc * 128 + rj + 96];
    #pragma unroll
    for (int off = 16; off > 0; off >>= 1) s += __shfl_down(s, off, 32);
    if (rj == 0) pooled[rc] = s;
  }
  __syncthreads();

  // ---- head ----
  if (tid < 10) {
    float acc = bh[d * 10 + tid];
    #pragma unroll
    for (int c3 = 0; c3 < 8; ++c3)
      acc = fmaf(pooled[c3] * (1.0f / 1021.0f), Wh[d * 80 + tid * 8 + c3], acc);
    part[((size_t)d * 512 + b) * 10 + tid] = z[d] * acc;
  }

  // ---- last-block fixed-order reduce (bitwise-deterministic value) ----
  __threadfence();               // release: part writes visible device-wide
  __syncthreads();
  if (tid == 0) {
    const unsigned int old = atomicAdd(counter, 1u);
    sflag = (old == 512u * 30u - 1u) ? 1 : 0;
  }
  __syncthreads();
  if (sflag) {
    __threadfence();             // acquire side
    for (int i = tid; i < 5120; i += 256) {
      float s = 0.0f;
      #pragma unroll
      for (int dd = 0; dd < 30; ++dd)   // fixed d-order; agent-scope loads
        s += __hip_atomic_load(&part[dd * 5120 + i],
                               __ATOMIC_RELAXED, __HIP_MEMORY_SCOPE_AGENT);
      out[i] = s;
    }
  }
}

// ---------------- fallback path: exact R7 fp32 kernel (60 partials) ----------------
__global__ __launch_bounds__(256, 6) void ensemble_kernel(
    const int* __restrict__ ids, const float* __restrict__ mask,
    const float* __restrict__ z, const float* __restrict__ tbl,
    const float* __restrict__ W1, const float* __restrict__ b1,
    const float* __restrict__ W2, const float* __restrict__ b2,
    const float* __restrict__ W3, const float* __restrict__ b3,
    const float* __restrict__ Wh, const float* __restrict__ bh,
    float* __restrict__ part)
{
  const int tid  = threadIdx.x;
  const int half = blockIdx.x & 1;
  const int bd   = blockIdx.x >> 1;
  const int b    = bd & 511;
  const int d    = bd >> 9;

  __shared__ float smem[4128];
  __shared__ float red[32];
  __shared__ float pooled[8];

  const int l_lo = half ? 1024 : 0;
  const int l_hi = half ? 2047 : 1029;
  const int j_lo = half ? 512  : 0;
  const int j_hi = half ? 1023 : 514;
  const int o_lo = half ? 512  : 0;
  const int o_hi = half ? 1021 : 512;

  const int*    idrow = ids  + (size_t)b * 4096;
  const float*  mrow  = mask + (size_t)b * 4096;
  const float4* tbl4  = (const float4*)tbl;
  const float*  w1p = W1 + d * 96;
  const float*  w2p = W2 + d * 96;
  const float*  w3p = W3 + d * 192;

  {
    float bia[4];
    #pragma unroll
    for (int c = 0; c < 4; ++c) bia[c] = b1[d * 4 + c];

    #pragma unroll 1
    for (int pass = 0; pass < 2; ++pass) {
      const int l0 = l_lo + 2 * tid + 512 * pass;
      const int p0 = 2 * l0;
      const int4   iv = *(const int4*)(idrow + p0);
      const float4 mv = *(const float4*)(mrow + p0);
      int i4; float m4;
      if (p0 + 4 < 4096) { i4 = idrow[p0 + 4]; m4 = mrow[p0 + 4]; }
      else               { i4 = 0;              m4 = 0.0f; }

      const int   pid[5] = {iv.x, iv.y, iv.z, iv.w, i4};
      const float pm[5]  = {mv.x, mv.y, mv.z, mv.w, m4};

      float a0[4], a1v[4];
      #pragma unroll
      for (int c = 0; c < 4; ++c) { a0[c] = bia[c]; a1v[c] = bia[c]; }

      #pragma unroll
      for (int q = 0; q < 5; ++q) {
        const float4 va = tbl4[(size_t)pid[q] * 2];
        const float4 vb = tbl4[(size_t)pid[q] * 2 + 1];
        const float xe[8] = {va.x * pm[q], va.y * pm[q], va.z * pm[q], va.w * pm[q],
                             vb.x * pm[q], vb.y * pm[q], vb.z * pm[q], vb.w * pm[q]};
        if (q <= 2) {
          #pragma unroll
          for (int c = 0; c < 4; ++c)
            #pragma unroll
            for (int e = 0; e < 8; ++e)
              a0[c] = fmaf(xe[e], w1p[c * 24 + e * 3 + q], a0[c]);
        }
        if (q >= 2) {
          #pragma unroll
          for (int c = 0; c < 4; ++c)
            #pragma unroll
            for (int e = 0; e < 8; ++e)
              a1v[c] = fmaf(xe[e], w1p[c * 24 + e * 3 + (q - 2)], a1v[c]);
        }
      }
      const int rel = l0 - l_lo;
      if (l0 + 1 < l_hi) {
        #pragma unroll
        for (int c = 0; c < 4; ++c)
          *(float2*)(smem + c * 1032 + rel) =
              make_float2(fmaxf(a0[c], 0.0f), fmaxf(a1v[c], 0.0f));
      } else if (l0 < l_hi) {
        #pragma unroll
        for (int c = 0; c < 4; ++c)
          smem[c * 1032 + rel] = fmaxf(a0[c], 0.0f);
      }
    }
    const int lt = l_lo + 1024 + tid;
    if (lt < l_hi) {
      float a0[4];
      #pragma unroll
      for (int c = 0; c < 4; ++c) a0[c] = bia[c];
      #pragma unroll
      for (int k = 0; k < 3; ++k) {
        const int p = 2 * lt + k;
        const int id = idrow[p];
        const float m = mrow[p];
        const float4 va = tbl4[(size_t)id * 2];
        const float4 vb = tbl4[(size_t)id * 2 + 1];
        const float xe[8] = {va.x*m, va.y*m, va.z*m, va.w*m,
                             vb.x*m, vb.y*m, vb.z*m, vb.w*m};
        #pragma unroll
        for (int cc = 0; cc < 4; ++cc)
          #pragma unroll
          for (int e = 0; e < 8; ++e)
            a0[cc] = fmaf(xe[e], w1p[cc * 24 + e * 3 + k], a0[cc]);
      }
      #pragma unroll
      for (int c = 0; c < 4; ++c)
        smem[c * 1032 + 1024 + tid] = fmaxf(a0[c], 0.0f);
    }
  }
  __syncthreads();

  float acc2[8][2], acc2t[8];
  {
    #pragma unroll
    for (int c2 = 0; c2 < 8; ++c2) {
      const float bb = b2[d * 8 + c2];
      acc2[c2][0] = bb; acc2[c2][1] = bb; acc2t[c2] = bb;
    }
    const int rel2  = 4 * tid;
    const bool tail2 = tid < (j_hi - j_lo - 512);
    #pragma unroll 1
    for (int c1 = 0; c1 < 4; ++c1) {
      float sw[8][3];
      #pragma unroll
      for (int c2 = 0; c2 < 8; ++c2)
        #pragma unroll
        for (int kk = 0; kk < 3; ++kk)
          sw[c2][kk] = w2p[c2 * 12 + c1 * 3 + kk];
      const float* hp = smem + c1 * 1032;
      const float4 h01 = *(const float4*)(hp + rel2);
      const float  h4v = hp[rel2 + 4];
      #pragma unroll
      for (int c2 = 0; c2 < 8; ++c2) {
        acc2[c2][0] = fmaf(h01.x, sw[c2][0], fmaf(h01.y, sw[c2][1],
                      fmaf(h01.z, sw[c2][2], acc2[c2][0])));
        acc2[c2][1] = fmaf(h01.z, sw[c2][0], fmaf(h01.w, sw[c2][1],
                      fmaf(h4v,   sw[c2][2], acc2[c2][1])));
      }
      if (tail2) {
        const float t0 = hp[1024 + 2 * tid], t1 = hp[1025 + 2 * tid],
                    t2 = hp[1026 + 2 * tid];
        #pragma unroll
        for (int c2 = 0; c2 < 8; ++c2)
          acc2t[c2] = fmaf(t0, sw[c2][0], fmaf(t1, sw[c2][1],
                      fmaf(t2, sw[c2][2], acc2t[c2])));
      }
    }
    #pragma unroll
    for (int c2 = 0; c2 < 8; ++c2) {
      acc2[c2][0] = fmaxf(acc2[c2][0], 0.0f);
      acc2[c2][1] = fmaxf(acc2[c2][1], 0.0f);
      acc2t[c2]   = fmaxf(acc2t[c2],   0.0f);
    }
    __syncthreads();
    const int j0 = j_lo + 2 * tid;
    const int jr = 2 * tid;
    if (j0 + 1 < j_hi) {
      #pragma unroll
      for (int c2 = 0; c2 < 8; ++c2)
        *(float2*)(smem + c2 * 516 + jr) = make_float2(acc2[c2][0], acc2[c2][1]);
    } else if (j0 < j_hi) {
      #pragma unroll
      for (int c2 = 0; c2 < 8; ++c2)
        smem[c2 * 516 + jr] = acc2[c2][0];
    }
    if (tid < (j_hi - j_lo - 512)) {
      #pragma unroll
      for (int c2 = 0; c2 < 8; ++c2)
        smem[c2 * 516 + 512 + tid] = acc2t[c2];
    }
  }
  __syncthreads();

  float acc3[8][2];
  #pragma unroll
  for (int cc = 0; cc < 8; ++cc) {
    const float bb = b3[d * 8 + cc];
    acc3[cc][0] = bb; acc3[cc][1] = bb;
  }
  {
    const int rel3 = 2 * tid;
    #pragma unroll 1
    for (int c2 = 0; c2 < 8; ++c2) {
      float sw[8][3];
      #pragma unroll
      for (int cc = 0; cc < 8; ++cc)
        #pragma unroll
        for (int kk = 0; kk < 3; ++kk)
          sw[cc][kk] = w3p[cc * 24 + c2 * 3 + kk];
      const float* hp = smem + c2 * 516;
      const float2 ha = *(const float2*)(hp + rel3);
      const float2 hb = *(const float2*)(hp + rel3 + 2);
      #pragma unroll
      for (int cc = 0; cc < 8; ++cc) {
        acc3[cc][0] = fmaf(ha.x, sw[cc][0], fmaf(ha.y, sw[cc][1],
                      fmaf(hb.x, sw[cc][2], acc3[cc][0])));
        acc3[cc][1] = fmaf(ha.y, sw[cc][0], fmaf(hb.x, sw[cc][1],
                      fmaf(hb.y, sw[cc][2], acc3[cc][1])));
      }
    }
  }
  const int i0 = o_lo + 2 * tid;
  float psum[8];
  #pragma unroll
  for (int cc = 0; cc < 8; ++cc) {
    float s = 0.0f;
    if (i0 < o_hi)     s += fmaxf(acc3[cc][0], 0.0f);
    if (i0 + 1 < o_hi) s += fmaxf(acc3[cc][1], 0.0f);
    psum[cc] = s;
  }

  const int lane = tid & 63;
  const int wid  = tid >> 6;
  #pragma unroll
  for (int c = 0; c < 8; ++c) {
    float v = psum[c];
    #pragma unroll
    for (int off = 32; off > 0; off >>= 1) v += __shfl_down(v, off, 64);
    if (lane == 0) red[wid * 8 + c] = v;
  }
  __syncthreads();
  if (tid < 8)
    pooled[tid] = red[tid] + red[8 + tid] + red[16 + tid] + red[24 + tid];
  __syncthreads();

  if (tid < 10) {
    float acc = (half == 0) ? bh[d * 10 + tid] : 0.0f;
    #pragma unroll
    for (int c3 = 0; c3 < 8; ++c3)
      acc = fmaf(pooled[c3] * (1.0f / 1021.0f), Wh[d * 80 + tid * 8 + c3], acc);
    part[(((size_t)d * 2 + half) * 512 + b) * 10 + tid] = z[d] * acc;
  }
}

__global__ __launch_bounds__(256) void reduce60_kernel(
    const float* __restrict__ part,   // [60][512][10]
    float* __restrict__ out)          // [512][10]
{
  const int i = blockIdx.x * 256 + threadIdx.x;
  float s = 0.0f;
  #pragma unroll
  for (int dd = 0; dd < 60; ++dd) s += part[dd * 5120 + i];
  out[i] = s;
}

extern "C" void kernel_launch(void* const* d_in, const int* in_sizes, int n_in,
                              void* d_out, int out_size, void* d_ws, size_t ws_size,
                              hipStream_t stream) {
  const int*   ids  = (const int*)d_in[0];
  const float* mask = (const float*)d_in[1];
  const float* z    = (const float*)d_in[2];
  const float* tbl  = (const float*)d_in[3];
  const float* W1   = (const float*)d_in[4];
  const float* b1   = (const float*)d_in[5];
  const float* W2   = (const float*)d_in[6];
  const float* b2   = (const float*)d_in[7];
  const float* W3   = (const float*)d_in[8];
  const float* b3   = (const float*)d_in[9];
  const float* Wh   = (const float*)d_in[10];
  const float* bh   = (const float*)d_in[11];
  float* out  = (float*)d_out;
  float* part = (float*)d_ws;

  const size_t part_bytes = 1228800;                       // max(30,60)-layout
  const size_t ctr_bytes  = 256;                           // counter slot
  const size_t wp_bytes   = 7680;                          // 1920 dwords
  const size_t a_bytes    = 30720;                         // [30][64][8] f16
  const size_t x_bytes    = (size_t)512 * 8 * 4096 * 2;    // 32 MiB f16
  const size_t need = part_bytes + ctr_bytes + wp_bytes + 2 * a_bytes + x_bytes;

  if (ws_size >= need) {
    unsigned int* ctr = (unsigned int*)((char*)d_ws + part_bytes);
    uint32_t* wp = (uint32_t*)((char*)d_ws + part_bytes + ctr_bytes);
    f16*      a2 = (f16*)((char*)d_ws + part_bytes + ctr_bytes + wp_bytes);
    f16*      a3 = (f16*)((char*)d_ws + part_bytes + ctr_bytes + wp_bytes + a_bytes);
    f16*      xh = (f16*)((char*)d_ws + part_bytes + ctr_bytes + wp_bytes + 2 * a_bytes);
    hipLaunchKernelGGL(prep_kernel, dim3(4096 + 19), dim3(256), 0, stream,
                       ids, mask, tbl, W1, W2, W3, xh, wp, a2, a3, ctr);
    hipLaunchKernelGGL(ensemble_f16_kernel, dim3(512 * 30), dim3(256), 0, stream,
                       xh, wp, a2, a3, z, b1, b2, b3, Wh, bh, part, ctr, out);
  } else {
    hipLaunchKernelGGL(ensemble_kernel, dim3(512 * 30 * 2), dim3(256), 0, stream,
                       ids, mask, z, tbl, W1, b1, W2, b2, W3, b3, Wh, bh, part);
    hipLaunchKernelGGL(reduce60_kernel, dim3(20), dim3(256), 0, stream, part, out);
  }
}

// Round 17
// 243.198 us; speedup vs baseline: 6.9710x; 6.9710x over previous
//
#include <hip/hip_runtime.h>
#include <stdint.h>

// FixedConv1DPriorEnsemble: DZ=30 ensemble of conv nets over embedded tokens.
// V=32000 E=8 DZ=30 C=10, CH=(4,8,8), K=3, S=(2,2,1), B=512, L=4096.
//
// History: R11 318.7 (f16 dot2); R13 256.3 (MFMA stages 2/3); R15 243.4 BEST
//   (merged full-sequence blocks, 3 nodes); R16 1695 CATASTROPHIC: last-block
//   reduce needs __threadfence() (device-scope release) in all 15360 blocks
//   -> per-XCD L2 writeback storm (VALUBusy 7%). Node-folding via cross-XCD
//   coherence is a dead end; revert to 3 nodes.
// R17: R15 skeleton + bank-conflict padding on BOTH LDS arrays:
//   h1 stride 2056->2066 f16 (1033 dwords, odd mod 32) and
//   h2 stride 1028->1034 f16 (517 dwords, odd mod 32): quad bank-sets
//   interleave even/odd -> max 2-way aliasing (free, m136).

typedef _Float16 f16;
typedef f16 f16x2 __attribute__((ext_vector_type(2)));
typedef f16 f16x4 __attribute__((ext_vector_type(4)));
typedef f16 f16x8 __attribute__((ext_vector_type(8)));
typedef float f32x4 __attribute__((ext_vector_type(4)));

#define H1S 2066   // h1 row stride (f16): 1033 dwords, odd mod 32
#define H2S 1034   // h2 row stride (f16): 517 dwords, odd mod 32

static __device__ __forceinline__ float dot2(f16x2 a, f16x2 b, float c) {
#if __has_builtin(__builtin_amdgcn_fdot2)
  return __builtin_amdgcn_fdot2(a, b, c, false);
#else
  return fmaf((float)a.x, (float)b.x, fmaf((float)a.y, (float)b.y, c));
#endif
}
static __device__ __forceinline__ f16x2 ldh(uint32_t u) {
  union { uint32_t u; f16x2 h; } v; v.u = u; return v.h;
}
static __device__ __forceinline__ uint32_t bch(f16x2 h) {
  union { uint32_t u; f16x2 h; } v; v.h = h; return v.u;
}
static __device__ __forceinline__ uint32_t packh(float a, float b) {
  f16x2 p; p.x = (f16)a; p.y = (f16)b; return bch(p);
}

// ---- prep: embed x_f16 + stage-1 dot2 weights + stage-2/3 MFMA A-frags ----
__global__ __launch_bounds__(256) void prep_kernel(
    const int* __restrict__ ids, const float* __restrict__ mask,
    const float* __restrict__ tbl,
    const float* __restrict__ W1, const float* __restrict__ W2,
    const float* __restrict__ W3,
    f16* __restrict__ x, uint32_t* __restrict__ wp,
    f16* __restrict__ a2, f16* __restrict__ a3) {
  const int blk = blockIdx.x;
  if (blk < 4096) {                            // embed: 2 tokens/thread
    const int b  = blk >> 3;
    const int l0 = ((blk & 7) * 256 + threadIdx.x) * 2;
    const int2   iv = *(const int2*)(ids + (size_t)b * 4096 + l0);
    const float2 mv = *(const float2*)(mask + (size_t)b * 4096 + l0);
    const float4* t4 = (const float4*)tbl;
    const float4 a0 = t4[(size_t)iv.x * 2], A1 = t4[(size_t)iv.x * 2 + 1];
    const float4 c0 = t4[(size_t)iv.y * 2], C1 = t4[(size_t)iv.y * 2 + 1];
    const float r0[8] = {a0.x, a0.y, a0.z, a0.w, A1.x, A1.y, A1.z, A1.w};
    const float r1[8] = {c0.x, c0.y, c0.z, c0.w, C1.x, C1.y, C1.z, C1.w};
    f16* xb = x + (size_t)b * 8 * 4096 + l0;
    #pragma unroll
    for (int e = 0; e < 8; ++e) {
      f16x2 p; p.x = (f16)(r0[e] * mv.x); p.y = (f16)(r1[e] * mv.y);
      *(f16x2*)(xb + e * 4096) = p;
    }
  } else {
    const int i = (blk - 4096) * 256 + threadIdx.x;
    if (i < 960) {                             // wp: 30*32
      const int d = i / 32, r = i % 32, e = r / 4, c = r % 4;
      const float* w = W1 + d * 96 + c * 24 + e * 3;
      wp[d * 64 + r * 2 + 0] = packh(w[0], w[1]);
      wp[d * 64 + r * 2 + 1] = packh(w[2], 0.0f);
    } else if (i < 2880) {                     // a2: 30*64
      const int idx = i - 960, d = idx >> 6, lane = idx & 63;
      const int quad = lane >> 4, m = lane & 15;
      f16x8 v;
      #pragma unroll
      for (int j = 0; j < 8; ++j) {
        float val = 0.0f;
        if (m < 8)  { if (j < 3)           val = W2[d * 96 + m * 12 + quad * 3 + j]; }
        else        { if (j >= 2 && j < 5) val = W2[d * 96 + (m - 8) * 12 + quad * 3 + (j - 2)]; }
        v[j] = (f16)val;
      }
      *(f16x8*)(a2 + ((size_t)d * 64 + lane) * 8) = v;
    } else if (i < 4800) {                     // a3: 30*64
      const int idx = i - 2880, d = idx >> 6, lane = idx & 63;
      const int quad = lane >> 4, m = lane & 15;
      f16x8 v;
      #pragma unroll
      for (int j = 0; j < 8; ++j) {
        const int c2 = quad * 2 + (j >> 2), t = j & 3;
        float val = 0.0f;
        if (m < 8)  { if (t < 3)  val = W3[d * 192 + m * 24 + c2 * 3 + t]; }
        else        { if (t >= 1) val = W3[d * 192 + (m - 8) * 24 + c2 * 3 + (t - 1)]; }
        v[j] = (f16)val;
      }
      *(f16x8*)(a3 + ((size_t)d * 64 + lane) * 8) = v;
    }
  }
}

// ---------------- fast path: one block per (b,d), full sequence ----------------
__global__ __launch_bounds__(256, 8) void ensemble_f16_kernel(
    const f16* __restrict__ x,        // [512][8][4096]
    const uint32_t* __restrict__ wp,  // stage-1 packed weights
    const f16* __restrict__ a2,       // stage-2 A-fragments [30][64][8]
    const f16* __restrict__ a3,       // stage-3 A-fragments [30][64][8]
    const float* __restrict__ z,
    const float* __restrict__ b1, const float* __restrict__ b2,
    const float* __restrict__ b3,
    const float* __restrict__ Wh, const float* __restrict__ bh,
    float* __restrict__ part)         // [30][512][10]
{
  const int tid = threadIdx.x;
  const int b   = blockIdx.x / 30;    // same-b blocks consecutive (x L2 reuse)
  const int d   = blockIdx.x - b * 30;

  // h1 f16[4][2066] (16528B); h2 f16[8][1034] (16544B) overlay;
  // pool f32[8][128] (4096B) overlay
  __shared__ float smem[4136];
  __shared__ float pooled[8];
  f16* h1f = (f16*)smem;
  f16* h2f = (f16*)smem;

  const f16*      xb  = x + (size_t)b * 8 * 4096;
  const uint32_t* wq1 = wp + d * 64;

  const int w = tid >> 6, lane = tid & 63, quad = lane >> 4, n = lane & 15;

  // zero h1 pads [2047,2066) x 4 rows (stage-2 tiles over-read up to 2051)
  if (tid < 76) h1f[(tid / 19) * H1S + 2047 + (tid % 19)] = (f16)0.0f;
  __syncthreads();

  // ---- stage 1: conv1 (E=8 -> 4ch, K=3, stride 2), dot2, 8 outputs/thread ----
  {
    float bia[4];
    #pragma unroll
    for (int c = 0; c < 4; ++c) bia[c] = b1[d * 4 + c];

    #pragma unroll
    for (int g = 0; g < 2; ++g) {
      const int l0 = 8 * tid + 4 * g;         // outputs l0..l0+3 (covers 0..2047)
      const int p0 = 2 * l0;                  // 16B-aligned byte offset
      const bool edge = (p0 + 8 >= 4096);     // only tid==255, g==1

      float A[4][4];
      #pragma unroll
      for (int c = 0; c < 4; ++c)
        #pragma unroll
        for (int o = 0; o < 4; ++o) A[c][o] = bia[c];

      #pragma unroll
      for (int e = 0; e < 8; ++e) {           // fully unrolled (R3 lesson)
        const f16* xe = xb + e * 4096 + p0;
        const f16x4 va = *(const f16x4*)xe;         // P0 P1
        const f16x4 vb = *(const f16x4*)(xe + 4);   // P2 P3
        f16x2 P4;
        if (edge) { P4.x = (f16)0.0f; P4.y = (f16)0.0f; }
        else      { P4 = *(const f16x2*)(xe + 8); }
        const f16x2 P0 = va.lo, P1 = va.hi, P2 = vb.lo, P3 = vb.hi;
        #pragma unroll
        for (int c = 0; c < 4; ++c) {
          const f16x2 w01 = ldh(wq1[(e * 4 + c) * 2]);
          const f16x2 w20 = ldh(wq1[(e * 4 + c) * 2 + 1]);
          A[c][0] = dot2(P0, w01, A[c][0]); A[c][0] = dot2(P1, w20, A[c][0]);
          A[c][1] = dot2(P1, w01, A[c][1]); A[c][1] = dot2(P2, w20, A[c][1]);
          A[c][2] = dot2(P2, w01, A[c][2]); A[c][2] = dot2(P3, w20, A[c][2]);
          A[c][3] = dot2(P3, w01, A[c][3]); A[c][3] = dot2(P4, w20, A[c][3]);
        }
      }
      if (l0 + 3 < 2047) {                    // all but tid255 g1
        #pragma unroll
        for (int c = 0; c < 4; ++c) {
          f16x4 p;
          p.x = (f16)fmaxf(A[c][0], 0.0f); p.y = (f16)fmaxf(A[c][1], 0.0f);
          p.z = (f16)fmaxf(A[c][2], 0.0f); p.w = (f16)fmaxf(A[c][3], 0.0f);
          *(f16x4*)(h1f + c * H1S + l0) = p;  // 8B-aligned ds_write_b64
        }
      } else {                                // tid255 g1: outputs 2044..2046
        #pragma unroll
        for (int c = 0; c < 4; ++c)
          #pragma unroll
          for (int o = 0; o < 4; ++o)
            if (l0 + o < 2047)
              h1f[c * H1S + l0 + o] = (f16)fmaxf(A[c][o], 0.0f);
      }
    }
  }
  __syncthreads();

  // ---- stage 2 (MFMA): rows 0-7 = c2 @ j, rows 8-15 = c2 @ j+1; 32 tiles ----
  f32x4 Ci[8];
  {
    const f16x8 af2 = *(const f16x8*)(a2 + ((size_t)d * 64 + lane) * 8);
    const f32x4 cinit2 = *(const f32x4*)(b2 + d * 8 + (quad & 1) * 4);
    #pragma unroll
    for (int i = 0; i < 8; ++i) {
      const int t = w + 4 * i;                // 0..31, all valid
      const f16* bp = h1f + quad * H1S + 64 * t + 4 * n;
      union { f16x8 v; f16x2 q[4]; } u;
      u.q[0] = *(const f16x2*)bp;
      u.q[1] = *(const f16x2*)(bp + 2);
      u.q[2] = *(const f16x2*)(bp + 4);
      u.q[3] = *(const f16x2*)(bp + 6);
      Ci[i] = __builtin_amdgcn_mfma_f32_16x16x32_f16(af2, u.v, cinit2, 0, 0, 0);
    }
  }
  __syncthreads();               // all h1 reads done; overlay h2

  {
    const int shift = quad >> 1;
    const int c2b   = (quad & 1) * 4;
    #pragma unroll
    for (int i = 0; i < 8; ++i) {
      const int t  = w + 4 * i;
      const int jl = 32 * t + 2 * n + shift;
      if (jl < 1023) {
        #pragma unroll
        for (int r = 0; r < 4; ++r)
          h2f[(c2b + r) * H2S + jl] = (f16)fmaxf(Ci[i][r], 0.0f);
      }
    }
    if (tid < 88)                // zero h2 pads [1023,1034) x 8 rows
      h2f[(tid / 11) * H2S + 1023 + (tid % 11)] = (f16)0.0f;
  }
  __syncthreads();

  // ---- stage 3 (MFMA): rows 0-7 = cc @ p, rows 8-15 = cc @ p+1; pool ----
  float pool4[4] = {0.0f, 0.0f, 0.0f, 0.0f};
  {
    const f16x8 af3 = *(const f16x8*)(a3 + ((size_t)d * 64 + lane) * 8);
    const f32x4 cinit3 = *(const f32x4*)(b3 + d * 8 + (quad & 1) * 4);
    const int c2a = quad * 2;
    #pragma unroll
    for (int i = 0; i < 8; ++i) {
      const int t = w + 4 * i;                // 0..31, all valid
      const f16* bp = h2f + c2a * H2S + 32 * t + 2 * n;
      union { f16x8 v; f16x2 q[4]; } u;
      u.q[0] = *(const f16x2*)bp;
      u.q[1] = *(const f16x2*)(bp + 2);
      u.q[2] = *(const f16x2*)(bp + H2S);
      u.q[3] = *(const f16x2*)(bp + H2S + 2);
      const f32x4 C = __builtin_amdgcn_mfma_f32_16x16x32_f16(af3, u.v, cinit3, 0, 0, 0);
      const int pl = 32 * t + 2 * n + (quad >> 1);
      if (pl < 1021) {
        #pragma unroll
        for (int r = 0; r < 4; ++r) pool4[r] += fmaxf(C[r], 0.0f);
      }
    }
  }

  // ---- pool reduction: smem f32[8][128], exact cover, then shuffle ----
  __syncthreads();               // stage-3 h2 reads complete before overwrite
  {
    const int cidx = w * 32 + (quad >> 1) * 16 + n;   // 0..127, unique
    const int ccb  = (quad & 1) * 4;
    #pragma unroll
    for (int r = 0; r < 4; ++r) smem[(ccb + r) * 128 + cidx] = pool4[r];
  }
  __syncthreads();
  {
    const int rc = tid >> 5;     // channel 0..7
    const int rj = tid & 31;
    float s = smem[rc * 128 + rj]      + smem[rc * 128 + rj + 32]
            + smem[rc * 128 + rj + 64] + smem[rc * 128 + rj + 96];
    #pragma unroll
    for (int off = 16; off > 0; off >>= 1) s += __shfl_down(s, off, 32);
    if (rj == 0) pooled[rc] = s;
  }
  __syncthreads();

  // ---- head ----
  if (tid < 10) {
    float acc = bh[d * 10 + tid];
    #pragma unroll
    for (int c3 = 0; c3 < 8; ++c3)
      acc = fmaf(pooled[c3] * (1.0f / 1021.0f), Wh[d * 80 + tid * 8 + c3], acc);
    part[((size_t)d * 512 + b) * 10 + tid] = z[d] * acc;
  }
}

// Fixed-order reduction over 30 d-partials: bitwise-deterministic.
__global__ __launch_bounds__(256) void reduce30_kernel(
    const float* __restrict__ part,   // [30][512][10]
    float* __restrict__ out)          // [512][10]
{
  const int i = blockIdx.x * 256 + threadIdx.x;   // 0..5119
  float s = 0.0f;
  #pragma unroll
  for (int dd = 0; dd < 30; ++dd) s += part[dd * 5120 + i];
  out[i] = s;
}

// ---------------- fallback path: exact R7 fp32 kernel (60 partials) ----------------
__global__ __launch_bounds__(256, 6) void ensemble_kernel(
    const int* __restrict__ ids, const float* __restrict__ mask,
    const float* __restrict__ z, const float* __restrict__ tbl,
    const float* __restrict__ W1, const float* __restrict__ b1,
    const float* __restrict__ W2, const float* __restrict__ b2,
    const float* __restrict__ W3, const float* __restrict__ b3,
    const float* __restrict__ Wh, const float* __restrict__ bh,
    float* __restrict__ part)
{
  const int tid  = threadIdx.x;
  const int half = blockIdx.x & 1;
  const int bd   = blockIdx.x >> 1;
  const int b    = bd & 511;
  const int d    = bd >> 9;

  __shared__ float smem[4128];
  __shared__ float red[32];
  __shared__ float pooled[8];

  const int l_lo = half ? 1024 : 0;
  const int l_hi = half ? 2047 : 1029;
  const int j_lo = half ? 512  : 0;
  const int j_hi = half ? 1023 : 514;
  const int o_lo = half ? 512  : 0;
  const int o_hi = half ? 1021 : 512;

  const int*    idrow = ids  + (size_t)b * 4096;
  const float*  mrow  = mask + (size_t)b * 4096;
  const float4* tbl4  = (const float4*)tbl;
  const float*  w1p = W1 + d * 96;
  const float*  w2p = W2 + d * 96;
  const float*  w3p = W3 + d * 192;

  {
    float bia[4];
    #pragma unroll
    for (int c = 0; c < 4; ++c) bia[c] = b1[d * 4 + c];

    #pragma unroll 1
    for (int pass = 0; pass < 2; ++pass) {
      const int l0 = l_lo + 2 * tid + 512 * pass;
      const int p0 = 2 * l0;
      const int4   iv = *(const int4*)(idrow + p0);
      const float4 mv = *(const float4*)(mrow + p0);
      int i4; float m4;
      if (p0 + 4 < 4096) { i4 = idrow[p0 + 4]; m4 = mrow[p0 + 4]; }
      else               { i4 = 0;              m4 = 0.0f; }

      const int   pid[5] = {iv.x, iv.y, iv.z, iv.w, i4};
      const float pm[5]  = {mv.x, mv.y, mv.z, mv.w, m4};

      float a0[4], a1v[4];
      #pragma unroll
      for (int c = 0; c < 4; ++c) { a0[c] = bia[c]; a1v[c] = bia[c]; }

      #pragma unroll
      for (int q = 0; q < 5; ++q) {
        const float4 va = tbl4[(size_t)pid[q] * 2];
        const float4 vb = tbl4[(size_t)pid[q] * 2 + 1];
        const float xe[8] = {va.x * pm[q], va.y * pm[q], va.z * pm[q], va.w * pm[q],
                             vb.x * pm[q], vb.y * pm[q], vb.z * pm[q], vb.w * pm[q]};
        if (q <= 2) {
          #pragma unroll
          for (int c = 0; c < 4; ++c)
            #pragma unroll
            for (int e = 0; e < 8; ++e)
              a0[c] = fmaf(xe[e], w1p[c * 24 + e * 3 + q], a0[c]);
        }
        if (q >= 2) {
          #pragma unroll
          for (int c = 0; c < 4; ++c)
            #pragma unroll
            for (int e = 0; e < 8; ++e)
              a1v[c] = fmaf(xe[e], w1p[c * 24 + e * 3 + (q - 2)], a1v[c]);
        }
      }
      const int rel = l0 - l_lo;
      if (l0 + 1 < l_hi) {
        #pragma unroll
        for (int c = 0; c < 4; ++c)
          *(float2*)(smem + c * 1032 + rel) =
              make_float2(fmaxf(a0[c], 0.0f), fmaxf(a1v[c], 0.0f));
      } else if (l0 < l_hi) {
        #pragma unroll
        for (int c = 0; c < 4; ++c)
          smem[c * 1032 + rel] = fmaxf(a0[c], 0.0f);
      }
    }
    const int lt = l_lo + 1024 + tid;
    if (lt < l_hi) {
      float a0[4];
      #pragma unroll
      for (int c = 0; c < 4; ++c) a0[c] = bia[c];
      #pragma unroll
      for (int k = 0; k < 3; ++k) {
        const int p = 2 * lt + k;
        const int id = idrow[p];
        const float m = mrow[p];
        const float4 va = tbl4[(size_t)id * 2];
        const float4 vb = tbl4[(size_t)id * 2 + 1];
        const float xe[8] = {va.x*m, va.y*m, va.z*m, va.w*m,
                             vb.x*m, vb.y*m, vb.z*m, vb.w*m};
        #pragma unroll
        for (int cc = 0; cc < 4; ++cc)
          #pragma unroll
          for (int e = 0; e < 8; ++e)
            a0[cc] = fmaf(xe[e], w1p[cc * 24 + e * 3 + k], a0[cc]);
      }
      #pragma unroll
      for (int c = 0; c < 4; ++c)
        smem[c * 1032 + 1024 + tid] = fmaxf(a0[c], 0.0f);
    }
  }
  __syncthreads();

  float acc2[8][2], acc2t[8];
  {
    #pragma unroll
    for (int c2 = 0; c2 < 8; ++c2) {
      const float bb = b2[d * 8 + c2];
      acc2[c2][0] = bb; acc2[c2][1] = bb; acc2t[c2] = bb;
    }
    const int rel2  = 4 * tid;
    const bool tail2 = tid < (j_hi - j_lo - 512);
    #pragma unroll 1
    for (int c1 = 0; c1 < 4; ++c1) {
      float sw[8][3];
      #pragma unroll
      for (int c2 = 0; c2 < 8; ++c2)
        #pragma unroll
        for (int kk = 0; kk < 3; ++kk)
          sw[c2][kk] = w2p[c2 * 12 + c1 * 3 + kk];
      const float* hp = smem + c1 * 1032;
      const float4 h01 = *(const float4*)(hp + rel2);
      const float  h4v = hp[rel2 + 4];
      #pragma unroll
      for (int c2 = 0; c2 < 8; ++c2) {
        acc2[c2][0] = fmaf(h01.x, sw[c2][0], fmaf(h01.y, sw[c2][1],
                      fmaf(h01.z, sw[c2][2], acc2[c2][0])));
        acc2[c2][1] = fmaf(h01.z, sw[c2][0], fmaf(h01.w, sw[c2][1],
                      fmaf(h4v,   sw[c2][2], acc2[c2][1])));
      }
      if (tail2) {
        const float t0 = hp[1024 + 2 * tid], t1 = hp[1025 + 2 * tid],
                    t2 = hp[1026 + 2 * tid];
        #pragma unroll
        for (int c2 = 0; c2 < 8; ++c2)
          acc2t[c2] = fmaf(t0, sw[c2][0], fmaf(t1, sw[c2][1],
                      fmaf(t2, sw[c2][2], acc2t[c2])));
      }
    }
    #pragma unroll
    for (int c2 = 0; c2 < 8; ++c2) {
      acc2[c2][0] = fmaxf(acc2[c2][0], 0.0f);
      acc2[c2][1] = fmaxf(acc2[c2][1], 0.0f);
      acc2t[c2]   = fmaxf(acc2t[c2],   0.0f);
    }
    __syncthreads();
    const int j0 = j_lo + 2 * tid;
    const int jr = 2 * tid;
    if (j0 + 1 < j_hi) {
      #pragma unroll
      for (int c2 = 0; c2 < 8; ++c2)
        *(float2*)(smem + c2 * 516 + jr) = make_float2(acc2[c2][0], acc2[c2][1]);
    } else if (j0 < j_hi) {
      #pragma unroll
      for (int c2 = 0; c2 < 8; ++c2)
        smem[c2 * 516 + jr] = acc2[c2][0];
    }
    if (tid < (j_hi - j_lo - 512)) {
      #pragma unroll
      for (int c2 = 0; c2 < 8; ++c2)
        smem[c2 * 516 + 512 + tid] = acc2t[c2];
    }
  }
  __syncthreads();

  float acc3[8][2];
  #pragma unroll
  for (int cc = 0; cc < 8; ++cc) {
    const float bb = b3[d * 8 + cc];
    acc3[cc][0] = bb; acc3[cc][1] = bb;
  }
  {
    const int rel3 = 2 * tid;
    #pragma unroll 1
    for (int c2 = 0; c2 < 8; ++c2) {
      float sw[8][3];
      #pragma unroll
      for (int cc = 0; cc < 8; ++cc)
        #pragma unroll
        for (int kk = 0; kk < 3; ++kk)
          sw[cc][kk] = w3p[cc * 24 + c2 * 3 + kk];
      const float* hp = smem + c2 * 516;
      const float2 ha = *(const float2*)(hp + rel3);
      const float2 hb = *(const float2*)(hp + rel3 + 2);
      #pragma unroll
      for (int cc = 0; cc < 8; ++cc) {
        acc3[cc][0] = fmaf(ha.x, sw[cc][0], fmaf(ha.y, sw[cc][1],
                      fmaf(hb.x, sw[cc][2], acc3[cc][0])));
        acc3[cc][1] = fmaf(ha.y, sw[cc][0], fmaf(hb.x, sw[cc][1],
                      fmaf(hb.y, sw[cc][2], acc3[cc][1])));
      }
    }
  }
  const int i0 = o_lo + 2 * tid;
  float psum[8];
  #pragma unroll
  for (int cc = 0; cc < 8; ++cc) {
    float s = 0.0f;
    if (i0 < o_hi)     s += fmaxf(acc3[cc][0], 0.0f);
    if (i0 + 1 < o_hi) s += fmaxf(acc3[cc][1], 0.0f);
    psum[cc] = s;
  }

  const int lane = tid & 63;
  const int wid  = tid >> 6;
  #pragma unroll
  for (int c = 0; c < 8; ++c) {
    float v = psum[c];
    #pragma unroll
    for (int off = 32; off > 0; off >>= 1) v += __shfl_down(v, off, 64);
    if (lane == 0) red[wid * 8 + c] = v;
  }
  __syncthreads();
  if (tid < 8)
    pooled[tid] = red[tid] + red[8 + tid] + red[16 + tid] + red[24 + tid];
  __syncthreads();

  if (tid < 10) {
    float acc = (half == 0) ? bh[d * 10 + tid] : 0.0f;
    #pragma unroll
    for (int c3 = 0; c3 < 8; ++c3)
      acc = fmaf(pooled[c3] * (1.0f / 1021.0f), Wh[d * 80 + tid * 8 + c3], acc);
    part[(((size_t)d * 2 + half) * 512 + b) * 10 + tid] = z[d] * acc;
  }
}

__global__ __launch_bounds__(256) void reduce60_kernel(
    const float* __restrict__ part,   // [60][512][10]
    float* __restrict__ out)          // [512][10]
{
  const int i = blockIdx.x * 256 + threadIdx.x;
  float s = 0.0f;
  #pragma unroll
  for (int dd = 0; dd < 60; ++dd) s += part[dd * 5120 + i];
  out[i] = s;
}

extern "C" void kernel_launch(void* const* d_in, const int* in_sizes, int n_in,
                              void* d_out, int out_size, void* d_ws, size_t ws_size,
                              hipStream_t stream) {
  const int*   ids  = (const int*)d_in[0];
  const float* mask = (const float*)d_in[1];
  const float* z    = (const float*)d_in[2];
  const float* tbl  = (const float*)d_in[3];
  const float* W1   = (const float*)d_in[4];
  const float* b1   = (const float*)d_in[5];
  const float* W2   = (const float*)d_in[6];
  const float* b2   = (const float*)d_in[7];
  const float* W3   = (const float*)d_in[8];
  const float* b3   = (const float*)d_in[9];
  const float* Wh   = (const float*)d_in[10];
  const float* bh   = (const float*)d_in[11];
  float* out  = (float*)d_out;
  float* part = (float*)d_ws;

  const size_t part_bytes = 1228800;                       // max(30,60)-layout
  const size_t wp_bytes   = 7680;                          // 1920 dwords
  const size_t a_bytes    = 30720;                         // [30][64][8] f16
  const size_t x_bytes    = (size_t)512 * 8 * 4096 * 2;    // 32 MiB f16
  const size_t need = part_bytes + wp_bytes + 2 * a_bytes + x_bytes;

  if (ws_size >= need) {
    uint32_t* wp = (uint32_t*)((char*)d_ws + part_bytes);
    f16*      a2 = (f16*)((char*)d_ws + part_bytes + wp_bytes);
    f16*      a3 = (f16*)((char*)d_ws + part_bytes + wp_bytes + a_bytes);
    f16*      xh = (f16*)((char*)d_ws + part_bytes + wp_bytes + 2 * a_bytes);
    hipLaunchKernelGGL(prep_kernel, dim3(4096 + 19), dim3(256), 0, stream,
                       ids, mask, tbl, W1, W2, W3, xh, wp, a2, a3);
    hipLaunchKernelGGL(ensemble_f16_kernel, dim3(512 * 30), dim3(256), 0, stream,
                       xh, wp, a2, a3, z, b1, b2, b3, Wh, bh, part);
    hipLaunchKernelGGL(reduce30_kernel, dim3(20), dim3(256), 0, stream, part, out);
  } else {
    hipLaunchKernelGGL(ensemble_kernel, dim3(512 * 30 * 2), dim3(256), 0, stream,
                       ids, mask, z, tbl, W1, b1, W2, b2, W3, b3, Wh, bh, part);
    hipLaunchKernelGGL(reduce60_kernel, dim3(20), dim3(256), 0, stream, part, out);
  }
}